// Round 1
// baseline (141.402 us; speedup 1.0000x reference)
//
#include <hip/hip_runtime.h>
#include <math.h>

// ---------------------------------------------------------------------------
// Kernel 1: scalar-conditioned MLP -> spline params -> per-interval cubic
// coefficients. Runs on a single thread (total work ~600 FLOPs + 32 sins).
//
// d_ws layout (floats):
//   ws[0..5]   : interior knot boundaries kk1..kk6 (for interval search)
//   ws[8+i*8 + 0..3] : cubic coeffs c0..c3 for interval i (k = 3+i), in u = x - tk
//   ws[8+i*8 + 4]    : tk (left knot of interval i)
// ---------------------------------------------------------------------------
__global__ void nsf_params_kernel(const float* __restrict__ a,
                                  const float* __restrict__ W1, const float* __restrict__ b1,
                                  const float* __restrict__ W2, const float* __restrict__ b2,
                                  const float* __restrict__ Ww, const float* __restrict__ bw,
                                  const float* __restrict__ Wk, const float* __restrict__ bk,
                                  float* __restrict__ ws)
{
    if (threadIdx.x != 0 || blockIdx.x != 0) return;

    const float av = a[0];
    float n1[16], n2[16];
    for (int j = 0; j < 16; ++j) n1[j] = sinf(av * W1[j] + b1[j]);
    for (int j = 0; j < 16; ++j) {
        float s = b2[j];
        for (int i = 0; i < 16; ++i) s += n1[i] * W2[i * 16 + j];
        n2[j] = sinf(s);
    }
    float w[9];
    for (int j = 0; j < 9; ++j) {
        float s = bw[j];
        for (int i = 0; i < 16; ++i) s += n2[i] * Ww[i * 9 + j];
        w[j] = s;
    }
    float kr[7];
    for (int j = 0; j < 7; ++j) {
        float s = bk[j];
        for (int i = 0; i < 16; ++i) s += n2[i] * Wk[i * 7 + j];
        kr[j] = s;
    }

    // softmax + cumsum -> knots in [0,1]
    float m = kr[0];
    for (int j = 1; j < 7; ++j) m = fmaxf(m, kr[j]);
    float e[7], se = 0.f;
    for (int j = 0; j < 7; ++j) { e[j] = expf(kr[j] - m); se += e[j]; }
    const float inv = 1.f / se;

    // padded knot vector t[14] = [0,0,0, 0, kk1..kk6, kk7, 1,1,1]
    float t[14], c[10];
    t[0] = t[1] = t[2] = t[3] = 0.f;
    float cum = 0.f;
    for (int j = 0; j < 7; ++j) { cum += e[j] * inv; t[4 + j] = cum; }
    t[11] = t[12] = t[13] = 1.f;

    // control points c[10] = [0, w0..w8]
    c[0] = 0.f;
    for (int j = 0; j < 9; ++j) c[1 + j] = w[j];

    // interior boundaries for the interval search (kk1..kk6)
    for (int j = 0; j < 6; ++j) ws[j] = t[4 + j];

    // For each interval k = 3..9: run de Boor symbolically in u = x - t[k].
    // Each d[j] is a cubic poly; alpha = (x - tlo)/(thi - tlo) = A + B*u.
    for (int i = 0; i < 7; ++i) {
        const int k = 3 + i;
        const float tk = t[k];
        float d[4][4];
        for (int j = 0; j < 4; ++j) {
            d[j][0] = c[k - 3 + j];
            d[j][1] = d[j][2] = d[j][3] = 0.f;
        }
        for (int r = 1; r <= 3; ++r) {
            for (int j = 3; j >= r; --j) {
                const float tlo = t[k + j - 3];
                const float thi = t[k + j + 1 - r];
                const float B = 1.f / (thi - tlo);       // always > 0 (see analysis)
                const float A = (tk - tlo) * B;
                float nd[4];
                for (int n = 0; n < 4; ++n) nd[n] = d[j - 1][n];
                for (int n = 0; n < r; ++n) {            // e = d[j]-d[j-1], deg r-1
                    const float en = d[j][n] - d[j - 1][n];
                    nd[n]     += A * en;
                    nd[n + 1] += B * en;
                }
                for (int n = 0; n < 4; ++n) d[j][n] = nd[n];
            }
        }
        ws[8 + i * 8 + 0] = d[3][0];
        ws[8 + i * 8 + 1] = d[3][1];
        ws[8 + i * 8 + 2] = d[3][2];
        ws[8 + i * 8 + 3] = d[3][3];
        ws[8 + i * 8 + 4] = tk;
    }
    ws[6] = 0.f; ws[7] = 0.f;  // unused pads (avoid reading poison into LDS semantics-free)
    for (int i = 0; i < 7; ++i) { ws[8 + i * 8 + 5] = 0.f; ws[8 + i * 8 + 6] = 0.f; ws[8 + i * 8 + 7] = 0.f; }
}

// ---------------------------------------------------------------------------
// Kernel 2: streaming spline evaluation. Memory-bound: 67 MB in + 67 MB out.
// ---------------------------------------------------------------------------
__device__ __forceinline__ float eval_one(float xv, const float* __restrict__ p,
                                          float k1, float k2, float k3,
                                          float k4, float k5, float k6)
{
    // xq = clip(x / sqrt(3), 0, 0.9999)
    float xq = fminf(fmaxf(xv * 0.57735026918962576f, 0.0f), 0.9999f);
    // digitize: count of interior knots <= xq  (side='right' semantics)
    int i = (xq >= k1) + (xq >= k2) + (xq >= k3) + (xq >= k4) + (xq >= k5) + (xq >= k6);
    const float4 cf = *reinterpret_cast<const float4*>(p + 8 + i * 8);
    const float u = xq - p[8 + i * 8 + 4];
    return fmaf(fmaf(fmaf(cf.w, u, cf.z), u, cf.y), u, cf.x);
}

__global__ __launch_bounds__(256) void nsf_eval_kernel(const float* __restrict__ x,
                                                       const float* __restrict__ ws,
                                                       float* __restrict__ out, int n)
{
    __shared__ __align__(16) float p[64];
    if (threadIdx.x < 64) p[threadIdx.x] = ws[threadIdx.x];
    __syncthreads();

    const float k1 = p[0], k2 = p[1], k3 = p[2], k4 = p[3], k5 = p[4], k6 = p[5];

    const int n4 = n >> 2;
    const int gid = blockIdx.x * blockDim.x + threadIdx.x;
    const int stride = gridDim.x * blockDim.x;

    const float4* __restrict__ x4 = reinterpret_cast<const float4*>(x);
    float4* __restrict__ o4 = reinterpret_cast<float4*>(out);

    for (int idx = gid; idx < n4; idx += stride) {
        const float4 v = x4[idx];
        float4 r;
        r.x = eval_one(v.x, p, k1, k2, k3, k4, k5, k6);
        r.y = eval_one(v.y, p, k1, k2, k3, k4, k5, k6);
        r.z = eval_one(v.z, p, k1, k2, k3, k4, k5, k6);
        r.w = eval_one(v.w, p, k1, k2, k3, k4, k5, k6);
        o4[idx] = r;
    }
    // tail (n % 4 != 0 safety; n = 256^3 here so this loop is empty)
    for (int j = (n4 << 2) + gid; j < n; j += stride)
        out[j] = eval_one(x[j], p, k1, k2, k3, k4, k5, k6);
}

extern "C" void kernel_launch(void* const* d_in, const int* in_sizes, int n_in,
                              void* d_out, int out_size, void* d_ws, size_t ws_size,
                              hipStream_t stream)
{
    const float* x  = (const float*)d_in[0];
    const float* a  = (const float*)d_in[1];
    const float* W1 = (const float*)d_in[2];
    const float* b1 = (const float*)d_in[3];
    const float* W2 = (const float*)d_in[4];
    const float* b2 = (const float*)d_in[5];
    const float* Ww = (const float*)d_in[6];
    const float* bw = (const float*)d_in[7];
    const float* Wk = (const float*)d_in[8];
    const float* bk = (const float*)d_in[9];
    float* out = (float*)d_out;
    float* ws  = (float*)d_ws;
    const int n = out_size;

    hipLaunchKernelGGL(nsf_params_kernel, dim3(1), dim3(64), 0, stream,
                       a, W1, b1, W2, b2, Ww, bw, Wk, bk, ws);

    // 2048 blocks x 256 threads = 8192 waves (32/CU): full occupancy for the
    // memory-bound streamer; each thread handles 8 float4s via grid-stride.
    hipLaunchKernelGGL(nsf_eval_kernel, dim3(2048), dim3(256), 0, stream,
                       x, ws, out, n);
}